// Round 3
// baseline (147.252 us; speedup 1.0000x reference)
//
#include <hip/hip_runtime.h>
#include <hip/hip_bf16.h>

typedef unsigned short ushort_t;
typedef unsigned int uint_t;

#define CIN   128
#define COUT  256
#define HH    56
#define WW    56
#define HWSZ  3136            // 56*56
#define BATCH 16
#define NPIX  50176           // 16*3136
#define KTOT  1152            // 128*9

typedef __attribute__((ext_vector_type(8))) short bf16x8;
typedef __attribute__((ext_vector_type(4))) float f32x4;

__device__ __forceinline__ ushort_t f2bf(float v) {
    union { float f; uint_t u; } c; c.f = v;
    uint_t u = c.u;
    u += 0x7FFFu + ((u >> 16) & 1u);   // RNE; inputs finite
    return (ushort_t)(u >> 16);
}

__device__ __forceinline__ uint_t pk2bf(float lo, float hi) {
    __hip_bfloat162 h = __float22bfloat162_rn(make_float2(lo, hi));  // x->low, y->high
    union { __hip_bfloat162 h; uint_t u; } c; c.h = h;
    return c.u;
}

// ---- fused prepass:
//  blocks [0,784):   input NCHW fp32 -> NHWC bf16 (64hw x 128ci tile, 2x2 reg transpose,
//                    packed bf16 cvt, XOR-swizzled b32 LDS writes -> conflict-free)
//  blocks [784,1040): weight OIHW fp32 -> bf16 [co][pos*128+ci], one co per block
//  block 784 zeroes the 16-byte guard page.
__global__ __launch_bounds__(256) void prep(
    const float* __restrict__ tensor, const float* __restrict__ weights,
    ushort_t* __restrict__ Ib, ushort_t* __restrict__ Wt, ushort_t* __restrict__ guard)
{
    __shared__ __align__(16) uint_t lds_u[64 * 68];   // 64 hw rows x 68 uints (=128ci + pad)
    const int tid = threadIdx.x;

    if (blockIdx.x < 784) {
        int t   = blockIdx.x;
        int b   = t / 49;
        int hwt = t - b * 49;
        int hw0 = hwt * 64;
        const float* src = tensor + (size_t)b * CIN * HWSZ + hw0;
        // 1024 tasks: hb = hw-block of 4, cp = ci-pair. Loads coalesced (16 lanes x 16B).
        for (int k = 0; k < 4; ++k) {
            int t2 = tid + k * 256;
            int hb = t2 & 15;
            int cp = t2 >> 4;                      // [0,64)
            const float* s0 = src + (size_t)(2 * cp) * HWSZ + hb * 4;
            float4 a  = *(const float4*)s0;
            float4 bb = *(const float4*)(s0 + HWSZ);
            uint_t w0 = pk2bf(a.x, bb.x);
            uint_t w1 = pk2bf(a.y, bb.y);
            uint_t w2 = pk2bf(a.z, bb.z);
            uint_t w3 = pk2bf(a.w, bb.w);
            int c16  = cp >> 2;
            int lb   = cp & 3;
            int c16p = c16 ^ (hb & 7);             // swizzle: row>>2 == hb for all 4 rows
            uint_t* base = &lds_u[(hb * 4) * 68 + c16p * 4 + lb];
            base[0 * 68] = w0;
            base[1 * 68] = w1;
            base[2 * 68] = w2;
            base[3 * 68] = w3;
        }
        __syncthreads();
        ushort_t* dst = Ib + ((size_t)b * HWSZ + hw0) * CIN;
        for (int k = 0; k < 4; ++k) {
            int s2  = tid + k * 256;               // 1024 = 64 rows x 16 chunks
            int ho  = s2 >> 4;
            int c16 = s2 & 15;
            int c16p = c16 ^ ((ho >> 2) & 7);
            uint4 v = *(const uint4*)&lds_u[ho * 68 + c16p * 4];
            *(uint4*)(dst + ho * 128 + c16 * 8) = v;   // coalesced 256B per 16 lanes
        }
    } else {
        int co = blockIdx.x - 784;
        ushort_t* lds_s = (ushort_t*)lds_u;
        const float* src = weights + (size_t)co * KTOT;
        for (int k = 0; k < 5; ++k) {
            int idx = tid + k * 256;
            if (idx < KTOT) {
                int ci  = idx / 9;
                int pos = idx - ci * 9;
                lds_s[pos * 128 + ci] = f2bf(src[idx]);   // coalesced fp32 read
            }
        }
        __syncthreads();
        ushort_t* dst = Wt + (size_t)co * KTOT;
        for (int k = 0; k < 5; ++k) {
            int idx = tid + k * 256;
            if (idx < KTOT) dst[idx] = lds_s[idx];        // coalesced bf16 write
        }
        if (blockIdx.x == 784 && tid < 8) guard[tid] = 0;
    }
}

// ---- main implicit-GEMM conv: C[co][pix] = sum_k Wt[co][k] * Ib[shift(pix,pos)][ci]
// True double-buffer: one barrier per k32-step; stage step s+1 AFTER barrier s so the
// vmcnt(0)-at-barrier drain sees loads that are a full iteration old.
// XOR chunk swizzle (cF = c ^ ((r>>1)&3)) makes fragment ds_read_b128 conflict-free.
__global__ __launch_bounds__(256) void conv_gemm(
    const ushort_t* __restrict__ Wt,   // [256][1152] bf16, k=(pos,ci)
    const ushort_t* __restrict__ Ib,   // [NPIX][128] bf16 NHWC
    const float* __restrict__ bias,
    float* __restrict__ out,
    const ushort_t* __restrict__ guard)
{
    __shared__ ushort_t A_lds[2][128 * 32];
    __shared__ ushort_t B_lds[2][128 * 32];

    const int tid  = threadIdx.x;
    const int wave = tid >> 6;
    const int lane = tid & 63;
    const int quad = lane >> 4;
    const int l16  = lane & 15;

    const int bm = blockIdx.x & 1;     // cout tile (0/1)
    const int bn = blockIdx.x >> 1;    // pixel tile (0..391)

    const int wm = (wave >> 1) * 64;   // wave's cout offset in tile
    const int wn = (wave & 1) * 64;    // wave's pixel offset in tile

    // staging slots: slot L = wave*128 + q*64 + lane; row r = L/4, chunk c = L&3
    // fetch chunk cF = c ^ ((r>>1)&3)  (XOR swizzle; LDS phys pos stays (r,c))
    const ushort_t* aCh[2];
    const ushort_t* pbCh[2];
    int py[2], px[2];
    for (int q = 0; q < 2; ++q) {
        int slot = wave * 128 + q * 64 + lane;
        int r  = slot >> 2;
        int c  = slot & 3;
        int cF = c ^ ((r >> 1) & 3);
        aCh[q] = Wt + (size_t)(bm * 128 + r) * KTOT + cF * 8;
        int pix = bn * 128 + r;
        int b_  = pix / HWSZ;
        int rem = pix - b_ * HWSZ;
        int y_  = rem / WW;
        int x_  = rem - y_ * WW;
        py[q] = y_; px[q] = x_;
        pbCh[q] = Ib + (size_t)pix * CIN + cF * 8;
    }
    const int ldsOff = (wave * 128) * 8;   // ushort offset of this wave's q=0 slot group
    const int xorc   = (l16 >> 1) & 3;     // read-side swizzle (wm/wn/i*16 are 16-aligned)

    const f32x4 zero = {0.f, 0.f, 0.f, 0.f};
    f32x4 acc[4][4];
    for (int i = 0; i < 4; ++i)
        for (int j = 0; j < 4; ++j) acc[i][j] = zero;

    // ---- staging lambda (step s -> pos=s>>2, cc=s&3) ----
    auto stage = [&](int s, int buf) {
        int pos = s >> 2;
        int cc  = s & 3;
        int p3  = pos / 3;
        int dy  = p3 - 1;
        int dx  = pos - p3 * 3 - 1;
        int shift = (dy * WW + dx) * CIN;
        for (int q = 0; q < 2; ++q) {
            __builtin_amdgcn_global_load_lds(
                (const __attribute__((address_space(1))) void*)(aCh[q] + pos * 128 + cc * 32),
                (__attribute__((address_space(3))) void*)(&A_lds[buf][ldsOff + q * 512]),
                16, 0, 0);
        }
        for (int q = 0; q < 2; ++q) {
            int yy = py[q] + dy, xx = px[q] + dx;
            bool ok = ((uint_t)yy < (uint_t)HH) && ((uint_t)xx < (uint_t)WW);
            const ushort_t* g = ok ? (pbCh[q] + shift + cc * 32) : guard;
            __builtin_amdgcn_global_load_lds(
                (const __attribute__((address_space(1))) void*)g,
                (__attribute__((address_space(3))) void*)(&B_lds[buf][ldsOff + q * 512]),
                16, 0, 0);
        }
    };

    stage(0, 0);
    for (int s = 0; s < 36; ++s) {
        __syncthreads();                       // drains prev stage (vmcnt(0) at barrier)
        if (s < 35) stage(s + 1, (s + 1) & 1); // prefetch next: a full iteration in flight
        const int p = s & 1;
        bf16x8 af[4], bfr[4];
        for (int i = 0; i < 4; ++i)
            af[i] = *(const bf16x8*)&A_lds[p][(wm + i * 16 + l16) * 32 + (quad ^ xorc) * 8];
        for (int j = 0; j < 4; ++j)
            bfr[j] = *(const bf16x8*)&B_lds[p][(wn + j * 16 + l16) * 32 + (quad ^ xorc) * 8];
        for (int i = 0; i < 4; ++i)
            for (int j = 0; j < 4; ++j)
                acc[i][j] = __builtin_amdgcn_mfma_f32_16x16x32_bf16(
                    af[i], bfr[j], acc[i][j], 0, 0, 0);
    }

    // epilogue: D row (quad*4+r) = cout, col (lane&15) = pixel (x-contiguous stores)
    int obase[4];
    for (int j = 0; j < 4; ++j) {
        int pix = bn * 128 + wn + j * 16 + l16;
        int b_  = pix / HWSZ;
        int rem = pix - b_ * HWSZ;
        obase[j] = b_ * (COUT * HWSZ) + rem;
    }
    for (int i = 0; i < 4; ++i) {
        for (int r = 0; r < 4; ++r) {
            int co = bm * 128 + wm + i * 16 + quad * 4 + r;
            float bv = bias[co];
            int coOff = co * HWSZ;
            for (int j = 0; j < 4; ++j) {
                out[(size_t)(obase[j] + coOff)] = acc[i][j][r] + bv;
            }
        }
    }
}

// ---- fallback (only if workspace is too small): direct fp32 conv
__global__ void naive_conv(const float* __restrict__ in, const float* __restrict__ w,
                           const float* __restrict__ bias, float* __restrict__ out, int total) {
    int idx = blockIdx.x * 256 + threadIdx.x;
    if (idx >= total) return;
    int x = idx % WW; int t = idx / WW;
    int y = t % HH; t /= HH;
    int co = t % COUT; int b = t / COUT;
    float s = bias[co];
    const float* wr = w + (size_t)co * KTOT;
    for (int ci = 0; ci < CIN; ++ci) {
        const float* ir = in + (size_t)(b * CIN + ci) * HWSZ;
        for (int kh = 0; kh < 3; ++kh) {
            int yy = y + kh - 1;
            if ((uint_t)yy >= (uint_t)HH) continue;
            for (int kw = 0; kw < 3; ++kw) {
                int xx = x + kw - 1;
                if ((uint_t)xx >= (uint_t)WW) continue;
                s += ir[yy * WW + xx] * wr[ci * 9 + kh * 3 + kw];
            }
        }
    }
    out[idx] = s;
}

extern "C" void kernel_launch(void* const* d_in, const int* in_sizes, int n_in,
                              void* d_out, int out_size, void* d_ws, size_t ws_size,
                              hipStream_t stream) {
    const float* tensor  = (const float*)d_in[0];
    const float* weights = (const float*)d_in[1];
    const float* bias    = (const float*)d_in[2];
    float* out = (float*)d_out;

    const size_t GUARD    = 1024;
    const size_t WT_BYTES = (size_t)COUT * KTOT * 2;   // 589824
    const size_t IB_BYTES = (size_t)NPIX * CIN * 2;    // 12845056
    const size_t NEED     = GUARD + WT_BYTES + IB_BYTES;

    if (ws_size >= NEED) {
        ushort_t* guard = (ushort_t*)d_ws;
        ushort_t* Wt    = (ushort_t*)((char*)d_ws + GUARD);
        ushort_t* Ib    = (ushort_t*)((char*)d_ws + GUARD + WT_BYTES);
        prep<<<784 + COUT, 256, 0, stream>>>(tensor, weights, Ib, Wt, guard);
        conv_gemm<<<(COUT / 128) * (NPIX / 128), 256, 0, stream>>>(Wt, Ib, bias, out, guard);
    } else {
        int total = BATCH * COUT * HWSZ;
        naive_conv<<<(total + 255) / 256, 256, 0, stream>>>(tensor, weights, bias, out, total);
    }
}

// Round 4
// 125.850 us; speedup vs baseline: 1.1701x; 1.1701x over previous
//
#include <hip/hip_runtime.h>
#include <hip/hip_bf16.h>

typedef unsigned short ushort_t;
typedef unsigned int uint_t;

#define CIN   128
#define COUT  256
#define HH    56
#define WW    56
#define HWSZ  3136            // 56*56
#define BATCH 16
#define NPIX  50176           // 16*3136
#define KTOT  1152            // 128*9

typedef __attribute__((ext_vector_type(8))) short bf16x8;
typedef __attribute__((ext_vector_type(4))) float f32x4;

__device__ __forceinline__ ushort_t f2bf(float v) {
    union { float f; uint_t u; } c; c.f = v;
    uint_t u = c.u;
    u += 0x7FFFu + ((u >> 16) & 1u);   // RNE; inputs finite
    return (ushort_t)(u >> 16);
}

__device__ __forceinline__ uint_t pk2bf(float lo, float hi) {
    __hip_bfloat162 h = __float22bfloat162_rn(make_float2(lo, hi));  // x->low, y->high
    union { __hip_bfloat162 h; uint_t u; } c; c.h = h;
    return c.u;
}

// ---- fused prepass:
//  blocks [0,784):   input NCHW fp32 -> NHWC bf16 (64hw x 128ci tile, 2x2 reg transpose,
//                    packed bf16 cvt, XOR-swizzled b32 LDS writes -> conflict-free)
//  blocks [784,1040): weight OIHW fp32 -> bf16 [co][pos*128+ci], one co per block
//  block 784 zeroes the 1KB guard page.
__global__ __launch_bounds__(256) void prep(
    const float* __restrict__ tensor, const float* __restrict__ weights,
    ushort_t* __restrict__ Ib, ushort_t* __restrict__ Wt, ushort_t* __restrict__ guard)
{
    __shared__ __align__(16) uint_t lds_u[64 * 68];   // 64 hw rows x 68 uints (=128ci + pad)
    const int tid = threadIdx.x;

    if (blockIdx.x < 784) {
        int t   = blockIdx.x;
        int b   = t / 49;
        int hwt = t - b * 49;
        int hw0 = hwt * 64;
        const float* src = tensor + (size_t)b * CIN * HWSZ + hw0;
        // 1024 tasks: hb = hw-block of 4, cp = ci-pair. Loads coalesced (16 lanes x 16B).
        #pragma unroll
        for (int k = 0; k < 4; ++k) {
            int t2 = tid + k * 256;
            int hb = t2 & 15;
            int cp = t2 >> 4;                      // [0,64)
            const float* s0 = src + (size_t)(2 * cp) * HWSZ + hb * 4;
            float4 a  = *(const float4*)s0;
            float4 bb = *(const float4*)(s0 + HWSZ);
            uint_t w0 = pk2bf(a.x, bb.x);
            uint_t w1 = pk2bf(a.y, bb.y);
            uint_t w2 = pk2bf(a.z, bb.z);
            uint_t w3 = pk2bf(a.w, bb.w);
            int c16  = cp >> 2;
            int lb   = cp & 3;
            int c16p = c16 ^ (hb & 7);             // swizzle: row>>2 == hb for all 4 rows
            uint_t* base = &lds_u[(hb * 4) * 68 + c16p * 4 + lb];
            base[0 * 68] = w0;
            base[1 * 68] = w1;
            base[2 * 68] = w2;
            base[3 * 68] = w3;
        }
        __syncthreads();
        ushort_t* dst = Ib + ((size_t)b * HWSZ + hw0) * CIN;
        #pragma unroll
        for (int k = 0; k < 4; ++k) {
            int s2  = tid + k * 256;               // 1024 = 64 rows x 16 chunks
            int ho  = s2 >> 4;
            int c16 = s2 & 15;
            int c16p = c16 ^ ((ho >> 2) & 7);
            uint4 v = *(const uint4*)&lds_u[ho * 68 + c16p * 4];
            *(uint4*)(dst + ho * 128 + c16 * 8) = v;   // coalesced 256B per 16 lanes
        }
    } else {
        int co = blockIdx.x - 784;
        ushort_t* lds_s = (ushort_t*)lds_u;
        const float* src = weights + (size_t)co * KTOT;
        #pragma unroll
        for (int k = 0; k < 5; ++k) {
            int idx = tid + k * 256;
            if (idx < KTOT) {
                int ci  = idx / 9;
                int pos = idx - ci * 9;
                lds_s[pos * 128 + ci] = f2bf(src[idx]);   // coalesced fp32 read
            }
        }
        __syncthreads();
        ushort_t* dst = Wt + (size_t)co * KTOT;
        #pragma unroll
        for (int k = 0; k < 5; ++k) {
            int idx = tid + k * 256;
            if (idx < KTOT) dst[idx] = lds_s[idx];        // coalesced bf16 write
        }
        if (blockIdx.x == 784 && tid < 128) ((uint_t*)guard)[tid] = 0;  // 512B zeros
    }
}

// ---- main implicit-GEMM conv: C[co][pix] = sum_k Wt[co][k] * Ib[shift(pix,pos)][ci]
// Double-buffered, FULLY UNROLLED 36-step K-loop: all staging addresses are
// precomputed (9x2 selected B pointers) or constant-folded (A: base + s*32 folds
// into the global offset field). One barrier per step; stage s+1 issued right
// after barrier s so its loads have a 16-MFMA iteration in flight before drain.
// XOR chunk swizzle keeps ds_read_b128 conflict-free (verified 0 in R3).
__global__ __launch_bounds__(256) void conv_gemm(
    const ushort_t* __restrict__ Wt,   // [256][1152] bf16, k=(pos,ci)
    const ushort_t* __restrict__ Ib,   // [NPIX][128] bf16 NHWC
    const float* __restrict__ bias,
    float* __restrict__ out,
    const ushort_t* __restrict__ guard)
{
    __shared__ ushort_t A_lds[2][128 * 32];
    __shared__ ushort_t B_lds[2][128 * 32];

    const int tid  = threadIdx.x;
    const int wave = tid >> 6;
    const int lane = tid & 63;
    const int quad = lane >> 4;
    const int l16  = lane & 15;

    // XCD-pairing swizzle: round-robin dispatch puts blk j and j+8 on the same
    // XCD; give them the same bn (B tile) and the two bm halves -> B fetched once.
    const int g  = blockIdx.x >> 4;          // [0,49)
    const int bm = (blockIdx.x >> 3) & 1;    // cout tile
    const int bn = g * 8 + (blockIdx.x & 7); // pixel tile [0,392)

    const int wm = (wave >> 1) * 64;   // wave's cout offset in tile
    const int wn = (wave & 1) * 64;    // wave's pixel offset in tile

    // staging slots: slot L = wave*128 + q*64 + lane; row r = L/4, chunk c = L&3
    // fetch chunk cF = c ^ ((r>>1)&3)  (XOR swizzle; LDS phys pos stays (r,c))
    const ushort_t* aCh[2];
    const ushort_t* pbCh[2];
    int py[2], px[2];
    #pragma unroll
    for (int q = 0; q < 2; ++q) {
        int slot = wave * 128 + q * 64 + lane;
        int r  = slot >> 2;
        int c  = slot & 3;
        int cF = c ^ ((r >> 1) & 3);
        aCh[q] = Wt + (size_t)(bm * 128 + r) * KTOT + cF * 8;
        int pix = bn * 128 + r;
        int b_  = pix / HWSZ;
        int rem = pix - b_ * HWSZ;
        int y_  = rem / WW;
        int x_  = rem - y_ * WW;
        py[q] = y_; px[q] = x_;
        pbCh[q] = Ib + (size_t)pix * CIN + cF * 8;
    }
    const int ldsOff = (wave * 128) * 8;   // ushort offset of this wave's q=0 slot group
    const int xorc   = (l16 >> 1) & 3;     // read-side swizzle

    // Precompute per-pos selected B pointers (bounds check + guard select ONCE).
    const ushort_t* bSel[9][2];
    #pragma unroll
    for (int pos = 0; pos < 9; ++pos) {
        const int dy = pos / 3 - 1;
        const int dx = pos % 3 - 1;
        #pragma unroll
        for (int q = 0; q < 2; ++q) {
            int yy = py[q] + dy, xx = px[q] + dx;
            bool ok = ((uint_t)yy < (uint_t)HH) && ((uint_t)xx < (uint_t)WW);
            bSel[pos][q] = ok ? (pbCh[q] + (dy * WW + dx) * CIN) : guard;
        }
    }

    const f32x4 zero = {0.f, 0.f, 0.f, 0.f};
    f32x4 acc[4][4];
    #pragma unroll
    for (int i = 0; i < 4; ++i)
        #pragma unroll
        for (int j = 0; j < 4; ++j) acc[i][j] = zero;

    auto stage = [&](int s, int buf) {
        const int pos = s >> 2;     // constant after unroll
        const int cc  = s & 3;
        #pragma unroll
        for (int q = 0; q < 2; ++q) {
            __builtin_amdgcn_global_load_lds(
                (const __attribute__((address_space(1))) void*)(aCh[q] + s * 32),
                (__attribute__((address_space(3))) void*)(&A_lds[buf][ldsOff + q * 512]),
                16, 0, 0);
            __builtin_amdgcn_global_load_lds(
                (const __attribute__((address_space(1))) void*)(bSel[pos][q] + cc * 32),
                (__attribute__((address_space(3))) void*)(&B_lds[buf][ldsOff + q * 512]),
                16, 0, 0);
        }
    };

    stage(0, 0);
    #pragma unroll
    for (int s = 0; s < 36; ++s) {
        __syncthreads();                       // drains stage s (vmcnt(0) at barrier)
        if (s < 35) stage(s + 1, (s + 1) & 1); // prefetch: full iteration in flight
        const int p = s & 1;
        bf16x8 af[4], bfr[4];
        #pragma unroll
        for (int i = 0; i < 4; ++i)
            af[i] = *(const bf16x8*)&A_lds[p][(wm + i * 16 + l16) * 32 + (quad ^ xorc) * 8];
        #pragma unroll
        for (int j = 0; j < 4; ++j)
            bfr[j] = *(const bf16x8*)&B_lds[p][(wn + j * 16 + l16) * 32 + (quad ^ xorc) * 8];
        #pragma unroll
        for (int i = 0; i < 4; ++i)
            #pragma unroll
            for (int j = 0; j < 4; ++j)
                acc[i][j] = __builtin_amdgcn_mfma_f32_16x16x32_bf16(
                    af[i], bfr[j], acc[i][j], 0, 0, 0);
    }

    // epilogue: D row (quad*4+r) = cout, col (lane&15) = pixel (x-contiguous stores)
    int obase[4];
    #pragma unroll
    for (int j = 0; j < 4; ++j) {
        int pix = bn * 128 + wn + j * 16 + l16;
        int b_  = pix / HWSZ;
        int rem = pix - b_ * HWSZ;
        obase[j] = b_ * (COUT * HWSZ) + rem;
    }
    #pragma unroll
    for (int i = 0; i < 4; ++i) {
        #pragma unroll
        for (int r = 0; r < 4; ++r) {
            int co = bm * 128 + wm + i * 16 + quad * 4 + r;
            float bv = bias[co];
            int coOff = co * HWSZ;
            #pragma unroll
            for (int j = 0; j < 4; ++j) {
                out[(size_t)(obase[j] + coOff)] = acc[i][j][r] + bv;
            }
        }
    }
}

// ---- fallback (only if workspace is too small): direct fp32 conv
__global__ void naive_conv(const float* __restrict__ in, const float* __restrict__ w,
                           const float* __restrict__ bias, float* __restrict__ out, int total) {
    int idx = blockIdx.x * 256 + threadIdx.x;
    if (idx >= total) return;
    int x = idx % WW; int t = idx / WW;
    int y = t % HH; t /= HH;
    int co = t % COUT; int b = t / COUT;
    float s = bias[co];
    const float* wr = w + (size_t)co * KTOT;
    for (int ci = 0; ci < CIN; ++ci) {
        const float* ir = in + (size_t)(b * CIN + ci) * HWSZ;
        for (int kh = 0; kh < 3; ++kh) {
            int yy = y + kh - 1;
            if ((uint_t)yy >= (uint_t)HH) continue;
            for (int kw = 0; kw < 3; ++kw) {
                int xx = x + kw - 1;
                if ((uint_t)xx >= (uint_t)WW) continue;
                s += ir[yy * WW + xx] * wr[ci * 9 + kh * 3 + kw];
            }
        }
    }
    out[idx] = s;
}

extern "C" void kernel_launch(void* const* d_in, const int* in_sizes, int n_in,
                              void* d_out, int out_size, void* d_ws, size_t ws_size,
                              hipStream_t stream) {
    const float* tensor  = (const float*)d_in[0];
    const float* weights = (const float*)d_in[1];
    const float* bias    = (const float*)d_in[2];
    float* out = (float*)d_out;

    const size_t GUARD    = 1024;
    const size_t WT_BYTES = (size_t)COUT * KTOT * 2;   // 589824
    const size_t IB_BYTES = (size_t)NPIX * CIN * 2;    // 12845056
    const size_t NEED     = GUARD + WT_BYTES + IB_BYTES;

    if (ws_size >= NEED) {
        ushort_t* guard = (ushort_t*)d_ws;
        ushort_t* Wt    = (ushort_t*)((char*)d_ws + GUARD);
        ushort_t* Ib    = (ushort_t*)((char*)d_ws + GUARD + WT_BYTES);
        prep<<<784 + COUT, 256, 0, stream>>>(tensor, weights, Ib, Wt, guard);
        conv_gemm<<<(COUT / 128) * (NPIX / 128), 256, 0, stream>>>(Wt, Ib, bias, out, guard);
    } else {
        int total = BATCH * COUT * HWSZ;
        naive_conv<<<(total + 255) / 256, 256, 0, stream>>>(tensor, weights, bias, out, total);
    }
}